// Round 5
// baseline (767.463 us; speedup 1.0000x reference)
//
#include <hip/hip_runtime.h>

// out[b,d,m] = (sum_n seg[b,d,n]*Wt[b,m,n]) / (sum_n Wt[b,m,n]),  Wt = W*(W>0.85)
// bs=4, d=16, n=4096. W = 268 MB read once -> memory floor ~43 us kernel.
// R5: NO LDS, NO barriers. seg read straight from L1/L2 per chunk; vmcnt
// in-order discipline: per chunk issue [seg loads]...[W-next loads LAST], so
// seg consumption (L2 ~200cy) never drains the in-flight W prefetch (HBM
// ~900cy) -- R3 had this inverted. seg consumed in quarter-groups (4 d) to
// keep live regs <=128 -> 4 blocks/CU, no dispatch tail (R4 ran 3/CU + tail).

typedef float v4f __attribute__((ext_vector_type(4)));

#define N_DIM 4096
#define D_DIM 16
#define THRESH 0.85f
#define RPW 4                  // rows per wave
#define CHUNK 256              // n per chunk (64 lanes x float4)
#define NCHUNK (N_DIM / CHUNK) // 16

__global__ __launch_bounds__(256, 4) void regu_kernel(
    const float* __restrict__ seg,   // [4][16][4096]
    const float* __restrict__ W,     // [4][4096][4096]
    float* __restrict__ out)         // [4][16][4096]
{
    const int lane = threadIdx.x & 63;
    const int wv   = threadIdx.x >> 6;
    const int row0 = blockIdx.x * 16 + wv * RPW;   // [0, 16384)
    const int b  = row0 >> 12;
    const int m0 = row0 & (N_DIM - 1);

    const float* Wp   = W   + ((size_t)b * N_DIM + m0) * N_DIM + lane * 4;
    const float* segp = seg + (size_t)b * D_DIM * N_DIM + lane * 4;

    float acc[RPW * D_DIM];                 // acc[r*16+d]
    float rowsum[RPW] = {0.f, 0.f, 0.f, 0.f};
#pragma unroll
    for (int i = 0; i < RPW * D_DIM; ++i) acc[i] = 0.f;

    v4f wA[RPW], wB[RPW];

    // prologue: W chunk 0 in flight
#pragma unroll
    for (int r = 0; r < RPW; ++r)
        wA[r] = __builtin_nontemporal_load((const v4f*)(Wp + (size_t)r * N_DIM));

    // one chunk. VMEM issue order inside: seg q0 | (use W-cur) | seg q1 |
    // seg q2 | seg q3 | W-next. All seg waits leave W-next in flight.
    auto body = [&](v4f* wcur, v4f* wnext, int c, bool prefetch) {
        const float* sp = segp + c * CHUNK;
        v4f s[4];

        // seg quarter 0 (d = 0..3)
#pragma unroll
        for (int q = 0; q < 4; ++q)
            s[q] = *(const v4f*)(sp + q * N_DIM);

        // threshold W-cur in place (vmcnt drains only the 4 oldest = W-cur)
#pragma unroll
        for (int r = 0; r < RPW; ++r) {
            v4f v = wcur[r];
            v.x = (v.x > THRESH) ? v.x : 0.f;
            v.y = (v.y > THRESH) ? v.y : 0.f;
            v.z = (v.z > THRESH) ? v.z : 0.f;
            v.w = (v.w > THRESH) ? v.w : 0.f;
            wcur[r] = v;
            rowsum[r] += (v.x + v.y) + (v.z + v.w);
        }

#pragma unroll
        for (int g = 0; g < 4; ++g) {          // quarter-groups of d
            v4f snext[4];
            if (g < 3) {                        // issue seg quarter g+1
#pragma unroll
                for (int q = 0; q < 4; ++q)
                    snext[q] = *(const v4f*)(sp + ((g + 1) * 4 + q) * N_DIM);
            } else if (prefetch) {              // last group: W-next LAST
#pragma unroll
                for (int r = 0; r < RPW; ++r)
                    wnext[r] = __builtin_nontemporal_load(
                        (const v4f*)(Wp + (size_t)(c + 1) * CHUNK + (size_t)r * N_DIM));
            }
            // consume seg quarter g
#pragma unroll
            for (int q = 0; q < 4; ++q) {
                const int d = g * 4 + q;
#pragma unroll
                for (int r = 0; r < RPW; ++r) {
                    acc[r * D_DIM + d] += wcur[r].x * s[q].x;
                    acc[r * D_DIM + d] += wcur[r].y * s[q].y;
                    acc[r * D_DIM + d] += wcur[r].z * s[q].z;
                    acc[r * D_DIM + d] += wcur[r].w * s[q].w;
                }
            }
#pragma unroll
            for (int q = 0; q < 4; ++q) s[q] = snext[q];
        }
    };

    for (int c = 0; c < NCHUNK; c += 2) {
        body(wA, wB, c, true);
        body(wB, wA, c + 1, c + 2 < NCHUNK);
    }

    // scatter-reduce 64 partials: after 6 steps lane l holds total for
    // index j = bitrev6(l)  (numerically verified R2-R4)
#pragma unroll
    for (int k = 0; k < 6; ++k) {
        const int S = 32 >> k;
        const bool up = (lane >> k) & 1;
#pragma unroll
        for (int j = 0; j < S; ++j) {
            const float mine = up ? acc[j + S] : acc[j];
            const float send = up ? acc[j] : acc[j + S];
            acc[j] = mine + __shfl_xor(send, 1 << k, 64);
        }
    }

#pragma unroll
    for (int r = 0; r < RPW; ++r) {
        float s = rowsum[r];
#pragma unroll
        for (int off = 1; off < 64; off <<= 1) s += __shfl_xor(s, off, 64);
        rowsum[r] = s;
    }

    const int j = __brev((unsigned)lane) >> 26;   // bitrev6
    const int r = j >> 4;
    const int d = j & 15;
    const float inv = 1.0f / (r < 2 ? (r == 0 ? rowsum[0] : rowsum[1])
                                    : (r == 2 ? rowsum[2] : rowsum[3]));
    out[((size_t)b * D_DIM + d) * N_DIM + (m0 + r)] = acc[0] * inv;
}

extern "C" void kernel_launch(void* const* d_in, const int* in_sizes, int n_in,
                              void* d_out, int out_size, void* d_ws, size_t ws_size,
                              hipStream_t stream) {
    const float* seg = (const float*)d_in[0];   // [4,16,64,64] fp32
    const float* W   = (const float*)d_in[1];   // [4,4096,4096] fp32
    float* out = (float*)d_out;                 // [4,16,64,64] fp32

    // 16384 rows / (4 waves x 4 rows) = 1024 blocks = 4 blocks/CU resident
    regu_kernel<<<1024, 256, 0, stream>>>(seg, W, out);
}